// Round 1
// baseline (122.000 us; speedup 1.0000x reference)
//
#include <hip/hip_runtime.h>

typedef unsigned int   u32;
typedef unsigned short u16;
typedef short bf16x8 __attribute__((ext_vector_type(8)));
typedef float f32x4  __attribute__((ext_vector_type(4)));

#define CIN   128
#define COUT  128
#define Hh    64
#define Ww    64
#define Bb    8
#define KPOS  9
#define KDIM  (CIN*KPOS)   // 1152
#define NKSTEP 36          // KDIM/32
#define XT_ELEMS (Bb*Hh*Ww*CIN)   // 4,194,304 ushorts (8 MB)

// ---- helpers ----------------------------------------------------------
__device__ __forceinline__ float bflo(u32 u){ return __uint_as_float(u << 16); }
__device__ __forceinline__ float bfhi(u32 u){ return __uint_as_float(u & 0xffff0000u); }

// round-to-nearest-even f32 -> bf16, packed pair (a -> low half). Branchless,
// inputs are finite so no NaN handling needed.
__device__ __forceinline__ u32 packbf(float a, float b){
    u32 ua = __float_as_uint(a);
    u32 ub = __float_as_uint(b);
    ua += 0x7fffu + ((ua >> 16) & 1u);
    ub += 0x7fffu + ((ub >> 16) & 1u);
    return (ua >> 16) | (ub & 0xffff0000u);
}
__device__ __forceinline__ u16 tobf(float a){
    u32 ua = __float_as_uint(a);
    ua += 0x7fffu + ((ua >> 16) & 1u);
    return (u16)(ua >> 16);
}

// ---- kernel 1: x [B,CIN,H,W] f32 -> xT [B,H,W,CIN] bf16 ---------------
// 32x32 tiles, LDS pad +1, paired-cin u32 stores.
__global__ __launch_bounds__(256) void k_transpose(const float* __restrict__ x,
                                                   u16* __restrict__ xT){
    __shared__ float tile[32*33];
    int bi = blockIdx.x;
    int st = bi & 127, ct = (bi >> 7) & 3, b = bi >> 9;
    int sb = st * 32, cb = ct * 32;
    int tid = threadIdx.x;

    int i = tid >> 5, j = tid & 31;
    const float* xp = x + ((size_t)(b*CIN + cb) * 4096) + sb;
#pragma unroll
    for (int rr = 0; rr < 4; ++rr){
        int ci = i + rr*8;
        tile[ci*33 + j] = xp[(size_t)ci*4096 + j];
    }
    __syncthreads();

    int ii = tid >> 4, jj = tid & 15;
    u32* outp = (u32*)xT + ((size_t)b*4096 + sb)*64 + (cb >> 1) + jj;
#pragma unroll
    for (int rr = 0; rr < 2; ++rr){
        int sl = ii + rr*16;
        float v0 = tile[(2*jj  )*33 + sl];
        float v1 = tile[(2*jj+1)*33 + sl];
        outp[(size_t)sl*64] = packbf(v0, v1);
    }
}

// ---- kernel 2: weight [COUT,CIN,3,3] f32 -> Wt bf16, A-fragment order --
// Wt[((kt*8+mt)*64+lane)*8 + jf] = W[m=mt*16+(lane&15)][ck=kt*32+(lane>>4)*8+jf]
// ck = kpos*CIN + cin ; src = (m*128+cin)*9 + kpos
__global__ __launch_bounds__(256) void k_wprep(const float* __restrict__ w,
                                               u16* __restrict__ Wt){
    int gid = blockIdx.x*256 + threadIdx.x;     // 0 .. 147455
    int jf   = gid & 7;
    int lane = (gid >> 3) & 63;
    int mt   = (gid >> 9) & 7;
    int kt   = gid >> 12;
    int m  = mt*16 + (lane & 15);
    int kk = (lane >> 4)*8 + jf;
    int ck = kt*32 + kk;
    int kpos = ck >> 7;
    int cin  = ck & 127;
    Wt[gid] = tobf(w[((size_t)m*128 + cin)*9 + kpos]);
}

// ---- kernel 3: fused deformable-im2col producer + MFMA GEMM -----------
// grid 256: block = (b = bi&7  -> XCD-local batch, t = bi>>3 -> 128-pos tile)
// C-tile 128(cout) x 128(pos); 4 waves in 2x2; each wave 4x4 16x16 tiles.
__global__ __launch_bounds__(256, 1)
void k_main(const float* __restrict__ off, const float* __restrict__ bias,
            const u16* __restrict__ xT, const u16* __restrict__ Wt,
            float* __restrict__ out){
    // V chunk: 128 rows(pos) x 32 bf16(k), row stride 20 dwords (80B) -> <=2-way banks
    __shared__ u32 Vsm[128*20];

    int tid = threadIdx.x;
    int bi  = blockIdx.x;
    int b   = bi & 7;
    int t   = bi >> 3;
    int s0  = t * 128;

    // producer identity: 2 threads per position (half-channels each)
    int p  = tid >> 1, hf = tid & 1;
    int ho = (s0 + p) >> 6;
    int wo = p & 63;
    const u16* xb_base = xT + (size_t)b * (Hh*Ww*CIN);

    // consumer identity
    int lane = tid & 63, wave = tid >> 6;
    int wm = wave >> 1, wn = wave & 1;
    int quad = lane >> 4, l16 = lane & 15;

    f32x4 acc[4][4];
#pragma unroll
    for (int i = 0; i < 4; ++i)
#pragma unroll
        for (int j = 0; j < 4; ++j) acc[i][j] = {0.f, 0.f, 0.f, 0.f};

    // persistent producer state (refreshed every 4th chunk = new kernel pos)
    int   aa[4] = {0,0,0,0};
    float wt[4] = {0.f,0.f,0.f,0.f};

    for (int ks = 0; ks < NKSTEP; ++ks){
        // A-fragment prefetch: coalesced 1KB/wave from pre-swizzled Wt
        uint4 araw[4];
#pragma unroll
        for (int i = 0; i < 4; ++i)
            araw[i] = *(const uint4*)(Wt + (size_t)(((ks*8 + wm*4 + i)*64 + lane))*8);

        if ((ks & 3) == 0){
            int kpos = ks >> 2;
            int kh = kpos / 3, kw = kpos - kh*3;
            size_t ob = ((size_t)(b*18 + 2*kpos))*4096 + (s0 + p);
            float dy = off[ob];
            float dx = off[ob + 4096];
            float py = (float)(ho + kh - 1) + dy;
            float px = (float)(wo + kw - 1) + dx;
            float y0f = floorf(py), x0f = floorf(px);
            float ly = py - y0f, lx = px - x0f;
            int y0 = (int)y0f, x0 = (int)x0f;
            int y1 = y0 + 1,  x1 = x0 + 1;
            float my0 = (y0 >= 0 && y0 < Hh) ? 1.f : 0.f;
            float my1 = (y1 >= 0 && y1 < Hh) ? 1.f : 0.f;
            float mx0 = (x0 >= 0 && x0 < Ww) ? 1.f : 0.f;
            float mx1 = (x1 >= 0 && x1 < Ww) ? 1.f : 0.f;
            float omly = 1.f - ly, omlx = 1.f - lx;
            wt[0] = omly*omlx*my0*mx0;   // (y0,x0)
            wt[1] = omly*lx  *my0*mx1;   // (y0,x1)
            wt[2] = ly  *omlx*my1*mx0;   // (y1,x0)
            wt[3] = ly  *lx  *my1*mx1;   // (y1,x1)
            int cy0 = min(max(y0,0),Hh-1), cy1 = min(max(y1,0),Hh-1);
            int cx0 = min(max(x0,0),Ww-1), cx1 = min(max(x1,0),Ww-1);
            aa[0] = (cy0*Ww + cx0)*CIN;
            aa[1] = (cy0*Ww + cx1)*CIN;
            aa[2] = (cy1*Ww + cx0)*CIN;
            aa[3] = (cy1*Ww + cx1)*CIN;
        }

        // gather 4 corners x 16 cin (2 x dwordx4 each), blend in f32, pack bf16
        int coff = ((ks & 3) << 5) + hf*16;
        const u16* xb = xb_base + coff;
        uint4 q[4][2];
#pragma unroll
        for (int c = 0; c < 4; ++c){
            q[c][0] = *(const uint4*)(xb + aa[c]);
            q[c][1] = *(const uint4*)(xb + aa[c] + 8);
        }
        u32 res[8];
#pragma unroll
        for (int d = 0; d < 8; ++d){
            float lo = 0.f, hi = 0.f;
#pragma unroll
            for (int c = 0; c < 4; ++c){
                u32 u = ((const u32*)&q[c][0])[d];
                lo = fmaf(wt[c], bflo(u), lo);
                hi = fmaf(wt[c], bfhi(u), hi);
            }
            res[d] = packbf(lo, hi);
        }

        __syncthreads();                       // consumers done with prev chunk
        u32* vrow = &Vsm[p*20 + hf*8];
        *(uint4*)(vrow    ) = *(uint4*)&res[0];
        *(uint4*)(vrow + 4) = *(uint4*)&res[4];
        __syncthreads();                       // V chunk visible

        // consume: B-fragments from LDS, 16 MFMAs
        uint4 braw[4];
#pragma unroll
        for (int j = 0; j < 4; ++j)
            braw[j] = *(const uint4*)&Vsm[((wn*4 + j)*16 + l16)*20 + quad*4];
#pragma unroll
        for (int i = 0; i < 4; ++i){
            bf16x8 av = __builtin_bit_cast(bf16x8, araw[i]);
#pragma unroll
            for (int j = 0; j < 4; ++j){
                bf16x8 bv = __builtin_bit_cast(bf16x8, braw[j]);
                acc[i][j] = __builtin_amdgcn_mfma_f32_16x16x32_bf16(av, bv, acc[i][j], 0, 0, 0);
            }
        }
    }

    // epilogue: D[row=quad*4+r][col=l16] (m89-verified C/D layout) + bias
#pragma unroll
    for (int i = 0; i < 4; ++i){
        int cout0 = (wm*4 + i)*16 + quad*4;
#pragma unroll
        for (int j = 0; j < 4; ++j){
            int pcol = (wn*4 + j)*16 + l16;
            size_t obase = ((size_t)(b*COUT + cout0))*4096 + (s0 + pcol);
#pragma unroll
            for (int r = 0; r < 4; ++r){
                out[obase + (size_t)r*4096] = acc[i][j][r] + bias[cout0 + r];
            }
        }
    }
}

// ---- launch -----------------------------------------------------------
extern "C" void kernel_launch(void* const* d_in, const int* in_sizes, int n_in,
                              void* d_out, int out_size, void* d_ws, size_t ws_size,
                              hipStream_t stream){
    const float* x    = (const float*)d_in[0];
    const float* off  = (const float*)d_in[1];
    const float* w    = (const float*)d_in[2];
    const float* bias = (const float*)d_in[3];
    float* out = (float*)d_out;

    u16* xT = (u16*)d_ws;            // 8 MB
    u16* Wt = xT + XT_ELEMS;         // 288 KB

    k_transpose<<<dim3(4096), dim3(256), 0, stream>>>(x, xT);
    k_wprep    <<<dim3(576),  dim3(256), 0, stream>>>(w, Wt);
    k_main     <<<dim3(256),  dim3(256), 0, stream>>>(off, bias, xT, Wt, out);
}

// Round 2
// 108.952 us; speedup vs baseline: 1.1198x; 1.1198x over previous
//
#include <hip/hip_runtime.h>

typedef unsigned int   u32;
typedef unsigned short u16;
typedef short bf16x8 __attribute__((ext_vector_type(8)));
typedef float f32x4  __attribute__((ext_vector_type(4)));

#define CIN   128
#define COUT  128
#define Hh    64
#define Ww    64
#define Bb    8
#define KPOS  9
#define KDIM  (CIN*KPOS)   // 1152
#define NKSTEP 36          // KDIM/32
#define XT_ELEMS (Bb*Hh*Ww*CIN)   // 4,194,304 ushorts (8 MB)

// ---- helpers ----------------------------------------------------------
__device__ __forceinline__ float bflo(u32 u){ return __uint_as_float(u << 16); }
__device__ __forceinline__ float bfhi(u32 u){ return __uint_as_float(u & 0xffff0000u); }

__device__ __forceinline__ u32 packbf(float a, float b){
    u32 ua = __float_as_uint(a);
    u32 ub = __float_as_uint(b);
    ua += 0x7fffu + ((ua >> 16) & 1u);
    ub += 0x7fffu + ((ub >> 16) & 1u);
    return (ua >> 16) | (ub & 0xffff0000u);
}
__device__ __forceinline__ u16 tobf(float a){
    u32 ua = __float_as_uint(a);
    ua += 0x7fffu + ((ua >> 16) & 1u);
    return (u16)(ua >> 16);
}

// ---- kernel 1: x [B,CIN,H,W] f32 -> xT [B,H,W,CIN] bf16 ---------------
__global__ __launch_bounds__(256) void k_transpose(const float* __restrict__ x,
                                                   u16* __restrict__ xT){
    __shared__ float tile[32*33];
    int bi = blockIdx.x;
    int st = bi & 127, ct = (bi >> 7) & 3, b = bi >> 9;
    int sb = st * 32, cb = ct * 32;
    int tid = threadIdx.x;

    int i = tid >> 5, j = tid & 31;
    const float* xp = x + ((size_t)(b*CIN + cb) * 4096) + sb;
#pragma unroll
    for (int rr = 0; rr < 4; ++rr){
        int ci = i + rr*8;
        tile[ci*33 + j] = xp[(size_t)ci*4096 + j];
    }
    __syncthreads();

    int ii = tid >> 4, jj = tid & 15;
    u32* outp = (u32*)xT + ((size_t)b*4096 + sb)*64 + (cb >> 1) + jj;
#pragma unroll
    for (int rr = 0; rr < 2; ++rr){
        int sl = ii + rr*16;
        float v0 = tile[(2*jj  )*33 + sl];
        float v1 = tile[(2*jj+1)*33 + sl];
        outp[(size_t)sl*64] = packbf(v0, v1);
    }
}

// ---- kernel 2: weight [COUT,CIN,3,3] f32 -> Wt bf16, A-fragment order --
// Wt[((kt*8+mt)*64+lane)*8 + jf] = W[m=mt*16+(lane&15)][ck=kt*32+(lane>>4)*8+jf]
__global__ __launch_bounds__(256) void k_wprep(const float* __restrict__ w,
                                               u16* __restrict__ Wt){
    int gid = blockIdx.x*256 + threadIdx.x;     // 0 .. 147455
    int jf   = gid & 7;
    int lane = (gid >> 3) & 63;
    int mt   = (gid >> 9) & 7;
    int kt   = gid >> 12;
    int m  = mt*16 + (lane & 15);
    int kk = (lane >> 4)*8 + jf;
    int ck = kt*32 + kk;
    int kpos = ck >> 7;
    int cin  = ck & 127;
    Wt[gid] = tobf(w[((size_t)m*128 + cin)*9 + kpos]);
}

// ---- kernel 3: fused deformable-im2col producer + MFMA GEMM -----------
// grid 512: b = bi&7 (XCD-local batch), t = bi>>3 -> 64-pos tile (= one ho row)
// C-tile 128(cout) x 64(pos); 4 waves 2x2: wm -> 64 cout, wn -> 32 pos.
// LDS double-buffered V chunk, single barrier per K-iter, next-chunk
// gathers + A-frags prefetched before current chunk's MFMAs.
__global__ __launch_bounds__(256, 2)
void k_main(const float* __restrict__ off, const float* __restrict__ bias,
            const u16* __restrict__ xT, const u16* __restrict__ Wt,
            float* __restrict__ out){
    // V chunk: 64 rows(pos) x 32 bf16(k); row stride 20 dwords (80B)
    __shared__ u32 Vsm[2][64*20];

    int tid = threadIdx.x;
    int bi  = blockIdx.x;
    int b   = bi & 7;
    int t   = bi >> 3;          // 0..63  == ho row
    int s0  = t * 64;

    // producer identity: 4 threads per position (8 cin each)
    int p  = tid >> 2, qt = tid & 3;
    int ho = t;
    int wo = p;
    const u16* xb_base = xT + (size_t)b * (Hh*Ww*CIN);

    // consumer identity
    int lane = tid & 63, wave = tid >> 6;
    int wm = wave >> 1, wn = wave & 1;
    int quad = lane >> 4, l16 = lane & 15;

    f32x4 acc[4][2];
#pragma unroll
    for (int i = 0; i < 4; ++i)
#pragma unroll
        for (int j = 0; j < 2; ++j) acc[i][j] = {0.f, 0.f, 0.f, 0.f};

    int   aa[4];
    float wt[4];

    // --- producer state for a kernel position ---
    auto state = [&](int kpos){
        int kh = kpos / 3, kw = kpos - kh*3;
        size_t ob = ((size_t)(b*18 + 2*kpos))*4096 + (s0 + p);
        float dy = off[ob];
        float dx = off[ob + 4096];
        float py = (float)(ho + kh - 1) + dy;
        float px = (float)(wo + kw - 1) + dx;
        float y0f = floorf(py), x0f = floorf(px);
        float ly = py - y0f, lx = px - x0f;
        int y0 = (int)y0f, x0 = (int)x0f;
        int y1 = y0 + 1,  x1 = x0 + 1;
        float my0 = (y0 >= 0 && y0 < Hh) ? 1.f : 0.f;
        float my1 = (y1 >= 0 && y1 < Hh) ? 1.f : 0.f;
        float mx0 = (x0 >= 0 && x0 < Ww) ? 1.f : 0.f;
        float mx1 = (x1 >= 0 && x1 < Ww) ? 1.f : 0.f;
        float omly = 1.f - ly, omlx = 1.f - lx;
        wt[0] = omly*omlx*my0*mx0;
        wt[1] = omly*lx  *my0*mx1;
        wt[2] = ly  *omlx*my1*mx0;
        wt[3] = ly  *lx  *my1*mx1;
        int cy0 = min(max(y0,0),Hh-1), cy1 = min(max(y1,0),Hh-1);
        int cx0 = min(max(x0,0),Ww-1), cx1 = min(max(x1,0),Ww-1);
        aa[0] = (cy0*Ww + cx0)*CIN;
        aa[1] = (cy0*Ww + cx1)*CIN;
        aa[2] = (cy1*Ww + cx0)*CIN;
        aa[3] = (cy1*Ww + cx1)*CIN;
    };

    auto gather = [&](int ks, uint4 q[4]){
        int coff = ((ks & 3) << 5) + qt*8;
        const u16* xb = xb_base + coff;
#pragma unroll
        for (int c = 0; c < 4; ++c)
            q[c] = *(const uint4*)(xb + aa[c]);
    };

    auto loadA = [&](int ks, uint4 a[4]){
#pragma unroll
        for (int i = 0; i < 4; ++i)
            a[i] = *(const uint4*)(Wt + (size_t)(((ks*8 + wm*4 + i)*64 + lane))*8);
    };

    auto blend_store = [&](const uint4 q[4], int buf){
        u32 res[4];
#pragma unroll
        for (int d = 0; d < 4; ++d){
            float lo = 0.f, hi = 0.f;
#pragma unroll
            for (int c = 0; c < 4; ++c){
                u32 u = ((const u32*)&q[0])[c*4 + d];
                lo = fmaf(wt[c], bflo(u), lo);
                hi = fmaf(wt[c], bfhi(u), hi);
            }
            res[d] = packbf(lo, hi);
        }
        *(uint4*)&Vsm[buf][p*20 + qt*4] = *(uint4*)&res[0];
    };

    // --- prologue: chunk 0 ---
    uint4 q[4], araw_cur[4], araw_nxt[4];
    state(0);
    gather(0, q);
    loadA(0, araw_cur);
    blend_store(q, 0);

    for (int ks = 0; ks < NKSTEP; ++ks){
        __syncthreads();               // V chunk ks visible in buf ks&1
        int nxt = ks + 1;
        bool have_nxt = (nxt < NKSTEP);
        if (have_nxt){
            if ((nxt & 3) == 0) state(nxt >> 2);
            gather(nxt, q);            // global loads in flight across MFMAs
            loadA(nxt, araw_nxt);
        }

        // consume chunk ks from Vsm[ks&1]
        uint4 braw[2];
#pragma unroll
        for (int j = 0; j < 2; ++j)
            braw[j] = *(const uint4*)&Vsm[ks & 1][((wn*2 + j)*16 + l16)*20 + quad*4];
#pragma unroll
        for (int i = 0; i < 4; ++i){
            bf16x8 av = __builtin_bit_cast(bf16x8, araw_cur[i]);
#pragma unroll
            for (int j = 0; j < 2; ++j){
                bf16x8 bv = __builtin_bit_cast(bf16x8, braw[j]);
                acc[i][j] = __builtin_amdgcn_mfma_f32_16x16x32_bf16(av, bv, acc[i][j], 0, 0, 0);
            }
        }

        if (have_nxt){
            blend_store(q, nxt & 1);
#pragma unroll
            for (int i = 0; i < 4; ++i) araw_cur[i] = araw_nxt[i];
        }
    }

    // epilogue: D[row=quad*4+r][col=l16] + bias
#pragma unroll
    for (int i = 0; i < 4; ++i){
        int cout0 = (wm*4 + i)*16 + quad*4;
#pragma unroll
        for (int j = 0; j < 2; ++j){
            int pcol = (wn*2 + j)*16 + l16;
            size_t obase = ((size_t)(b*COUT + cout0))*4096 + (s0 + pcol);
#pragma unroll
            for (int r = 0; r < 4; ++r){
                out[obase + (size_t)r*4096] = acc[i][j][r] + bias[cout0 + r];
            }
        }
    }
}

// ---- launch -----------------------------------------------------------
extern "C" void kernel_launch(void* const* d_in, const int* in_sizes, int n_in,
                              void* d_out, int out_size, void* d_ws, size_t ws_size,
                              hipStream_t stream){
    const float* x    = (const float*)d_in[0];
    const float* off  = (const float*)d_in[1];
    const float* w    = (const float*)d_in[2];
    const float* bias = (const float*)d_in[3];
    float* out = (float*)d_out;

    u16* xT = (u16*)d_ws;            // 8 MB
    u16* Wt = xT + XT_ELEMS;         // 288 KB

    k_transpose<<<dim3(4096), dim3(256), 0, stream>>>(x, xT);
    k_wprep    <<<dim3(576),  dim3(256), 0, stream>>>(w, Wt);
    k_main     <<<dim3(512),  dim3(256), 0, stream>>>(off, bias, xT, Wt, out);
}